// Round 15
// baseline (2033.751 us; speedup 1.0000x reference)
//
#include <hip/hip_runtime.h>
#include <cstdint>
#include <cstddef>

// DecoderLSTM: 2-layer LSTM (B=512,H=512,T=128) + 3-layer MLP head.
// fp16 datapath, fp32 accum + fp32 cell state. K-split pipelining (round 5):
// gates_s = X_s@Wx + H_s@Wh; H-half computed one dispatch early by 256 partial
// blocks while 256 completion blocks finish the current step (512 blocks, 2/CU).
// Round 15: LSTM K-loop re-chunked BK=64 -> BK=128: 4 chunks, 2 bufs x 32KB
// (64KB/block, still 2 blocks/CU), conservative __syncthreads-per-chunk
// (r11-proven pattern; DMA hides under the 2x-longer compute). Halves the
// sync rounds. Swapped-operand MFMA + in-register cell update = r12-exact.
// MLP = r14-exact (neutral vs r6 -> at its memory floor).

using u16 = unsigned short;
typedef __attribute__((ext_vector_type(8))) _Float16 f16x8;
typedef __attribute__((ext_vector_type(4))) float f32x4;

__device__ __forceinline__ u16 f2h(float f) {
    union { _Float16 h; u16 u; } v; v.h = (_Float16)f; return v.u;
}
__device__ __forceinline__ float h2f(u16 u) {
    union { u16 u; _Float16 h; } v; v.u = u; return (float)v.h;
}
__device__ __forceinline__ float tanh_fast(float v) {
    float a = fabsf(v);
    float t = __expf(-2.f * a);
    float r = (1.f - t) / (1.f + t);
    return copysignf(r, v);
}
__device__ __forceinline__ float sigmoid_fast(float v) {
    return 1.f / (1.f + __expf(-v));
}

__device__ __forceinline__ void gl_lds16(const u16* g, char* l) {
    __builtin_amdgcn_global_load_lds((const __attribute__((address_space(1))) char*)(const char*)g,
                                     (__attribute__((address_space(3))) char*)l, 16, 0, 0);
}

// Swizzled LDS read, 8-unit rows (tile [rows][64 f16]): unit u' holds global
// col-unit u'^(row&7). Involution applied to global src on stage and to the
// read index (both sides, rule #21). Used by MLP.
__device__ __forceinline__ f16x8 lds_read_sw(const u16* tile, int row, int cu) {
    int unit = (row << 3) | (cu ^ (row & 7));
    return *(const f16x8*)&tile[unit << 3];
}

// Swizzled LDS read, 16-unit rows (tile [rows][128 f16]): XOR involution on
// the low 3 bits of the column-unit; bit 3 passes through. Round-trip verified:
// reader(row,cu) -> unit u=(cu&8)|((cu&7)^(row&7)); staged global col there =
// (u&8)|((u&7)^(row&7)) = cu.
__device__ __forceinline__ f16x8 lds_read_sw16(const u16* tile, int row, int cu) {
    int unit = (row << 4) | (cu & 8) | ((cu & 7) ^ (row & 7));
    return *(const f16x8*)&tile[unit << 3];
}

// ---------------------------------------------------------------- prepack ----
// Bpack[l][np][k] (f16), np = hcol*4 + gate (i,f,g,o), k: 0..511 = W_ih, 512..1023 = W_hh
__global__ __launch_bounds__(256) void prepack(
    const float* __restrict__ W_ih, const float* __restrict__ W_hh,
    const float* __restrict__ b_ih, const float* __restrict__ b_hh,
    const float* __restrict__ fc1w, const float* __restrict__ fc2w, const float* __restrict__ fc3w,
    u16* __restrict__ Bpack, float* __restrict__ bsumv, u16* __restrict__ fcw)
{
    int stride = gridDim.x * blockDim.x;
    int tid0 = blockIdx.x * blockDim.x + threadIdx.x;
    for (int idx = tid0; idx < 2 * 2048 * 1024; idx += stride) {
        int l = idx >> 21;
        int rem = idx & ((1 << 21) - 1);
        int np = rem >> 10;
        int k = rem & 1023;
        int n = (np & 3) * 512 + (np >> 2);
        float v = (k < 512) ? W_ih[((size_t)l * 2048 + n) * 512 + k]
                            : W_hh[((size_t)l * 2048 + n) * 512 + (k - 512)];
        Bpack[idx] = f2h(v);
    }
    for (int idx = tid0; idx < 2 * 2048; idx += stride) {
        int l = idx >> 11;
        int np = idx & 2047;
        int n = (np & 3) * 512 + (np >> 2);
        bsumv[idx] = b_ih[l * 2048 + n] + b_hh[l * 2048 + n];
    }
    for (int idx = tid0; idx < 3 * 512 * 512; idx += stride) {
        const float* w = idx < 262144 ? fc1w : (idx < 524288 ? fc2w : fc3w);
        fcw[idx] = f2h(w[idx & 262143]);
    }
}

// A buffers: [512][1024] f16: cols [0:512) = X (x / hsum / h0-as-X), [512:1024) = h
__global__ __launch_bounds__(256) void initbufs(
    const float* __restrict__ x, u16* __restrict__ A0_0, u16* __restrict__ A1_0,
    float* __restrict__ c0, float* __restrict__ c1, float* __restrict__ gb0)
{
    int stride = gridDim.x * blockDim.x;
    int tid0 = blockIdx.x * blockDim.x + threadIdx.x;
    for (int idx = tid0; idx < 512 * 512; idx += stride) {
        int row = idx >> 9, col = idx & 511;
        size_t b = (size_t)row * 1024;
        A0_0[b + col] = f2h(x[idx]);
        A1_0[b + 512 + col] = 0;     // h1(-1) = 0
        c0[idx] = 0.f;               // c layout [hcol][batch]
        c1[idx] = 0.f;
    }
    for (int idx = tid0; idx < 1048576; idx += stride) gb0[idx] = 0.f;  // H-half of step 0
}

// --------------------------------------------------------------- lstm phase --
// 512 blocks x 256 thr (2/CU). Blocks 0..255: completion (gates = gbufR + X@W_x,
// in-register epilogue). Blocks 256..511: partial (gbufW = H@W_h). 64 batch x
// 64 n'-cols, K=512 in 4 chunks of 128; 2 bufs x (A 16K | W 16K) = 64KB;
// conservative __syncthreads-per-chunk, stage(c+1) after sync (DMA hides under
// compute). MFMA operands SWAPPED (gates^T = W.X^T): lane's 4 acc regs = gates
// i,f,g,o of ONE cell.
template <int IS_L1>
__global__ __launch_bounds__(256) void lstm_phase(
    const u16* __restrict__ Ax, const u16* __restrict__ Ah, int hoffH,
    const u16* __restrict__ Wc, const u16* __restrict__ Wp,
    const float* __restrict__ gbufR, float* __restrict__ gbufW,
    const float* __restrict__ bsumv, float* __restrict__ cbuf,
    u16* __restrict__ hdst, const u16* __restrict__ h0src,
    u16* __restrict__ hsumdst, u16* __restrict__ seqdst)
{
    __shared__ char smem[65536];   // 2 bufs x (A 16K | W 16K)

    const int id = blockIdx.x;
    const bool isPartial = id >= 256;
    const int rid = id & 255;
    const int xcd = rid & 7, slot = rid >> 3;
    const int nb = xcd * 4 + (slot & 3);   // 0..31
    const int rg = slot >> 2;              // 0..7
    const int n0 = nb * 64;
    const int row0 = rg * 64;
    const int tile = rg * 32 + nb;

    const u16* Abase = isPartial ? Ah : Ax;
    const int xoff = isPartial ? hoffH : 0;
    const u16* Wbase = isPartial ? Wp : Wc;

    const int tid = threadIdx.x;
    const int lane = tid & 63, wid = tid >> 6;
    const int wm = (wid >> 1) * 32, wn = (wid & 1) * 32;
    const int fm = lane & 15, q = lane >> 4;

    // staging: per chunk each tile = 64 rows x 16 units (1024 16B-units);
    // wave w stages units [w*256, w*256+256) via 4 instrs; global src
    // pre-swizzled by the 16-unit involution (low-3-bit XOR, bit 3 passthrough).
    size_t aOff[4], wOff[4];
#pragma unroll
    for (int i = 0; i < 4; ++i) {
        int s = wid * 256 + i * 64 + lane;
        int r = s >> 4;
        int u = s & 15;
        int csw = (u & 8) | ((u & 7) ^ (r & 7));
        aOff[i] = (size_t)(row0 + r) * 1024 + xoff + csw * 8;
        wOff[i] = (size_t)(n0 + r) * 1024 + csw * 8;
    }
    const int dW = wid * 4096;

    f32x4 acc[2][2];
    acc[0][0] = (f32x4)0.f; acc[0][1] = (f32x4)0.f;
    acc[1][0] = (f32x4)0.f; acc[1][1] = (f32x4)0.f;

    auto stage = [&](char* buf, int k0) {
#pragma unroll
        for (int i = 0; i < 4; ++i) {
            gl_lds16(Abase + aOff[i] + k0, buf + dW + i * 1024);
            gl_lds16(Wbase + wOff[i] + k0, buf + 16384 + dW + i * 1024);
        }
    };

    char* bc = smem;            // current buffer
    char* bn = smem + 32768;    // next buffer

    stage(bc, 0);

    for (int c = 0; c < 4; ++c) {
        __syncthreads();                 // drains own DMA (vmcnt 0) + all waves arrived
        if (c < 3) stage(bn, (c + 1) * 128);
        __builtin_amdgcn_sched_barrier(0);

        const u16* sA = (const u16*)bc;
        const u16* sB = (const u16*)(bc + 16384);

#pragma unroll
        for (int kf = 0; kf < 4; ++kf) {
            const int cu = kf * 4 + q;
            f16x8 b0 = lds_read_sw16(sB, wn + fm, cu);        // W rows wn..wn+15   (A-op)
            f16x8 b1 = lds_read_sw16(sB, wn + 16 + fm, cu);   // W rows wn+16..+31
            f16x8 a0 = lds_read_sw16(sA, wm + fm, cu);        // X rows wm..wm+15   (B-op)
            f16x8 a1 = lds_read_sw16(sA, wm + 16 + fm, cu);   // X rows wm+16..+31
            // swapped: D = W · X^T ; acc[i][j] = n'-frag i, batch-frag j
            acc[0][0] = __builtin_amdgcn_mfma_f32_16x16x32_f16(b0, a0, acc[0][0], 0, 0, 0);
            acc[0][1] = __builtin_amdgcn_mfma_f32_16x16x32_f16(b0, a1, acc[0][1], 0, 0, 0);
            acc[1][0] = __builtin_amdgcn_mfma_f32_16x16x32_f16(b1, a0, acc[1][0], 0, 0, 0);
            acc[1][1] = __builtin_amdgcn_mfma_f32_16x16x32_f16(b1, a1, acc[1][1], 0, 0, 0);
        }

        char* t = bc; bc = bn; bn = t;
    }

    // ---------------- partial role: dump fragments to gbufW, done --------------
    if (isPartial) {
        float* dst = gbufW + (size_t)tile * 4096 + wid * 1024 + lane * 4;
        *(f32x4*)(dst +   0) = acc[0][0];
        *(f32x4*)(dst + 256) = acc[0][1];
        *(f32x4*)(dst + 512) = acc[1][0];
        *(f32x4*)(dst + 768) = acc[1][1];
        return;
    }

    // ---------------- completion role: add partial, in-register LSTM cell ------
    {
        const float* src = gbufR + (size_t)tile * 4096 + wid * 1024 + lane * 4;
        acc[0][0] += *(const f32x4*)(src +   0);
        acc[0][1] += *(const f32x4*)(src + 256);
        acc[1][0] += *(const f32x4*)(src + 512);
        acc[1][1] += *(const f32x4*)(src + 768);
    }

    __syncthreads();               // last chunk's reads retired; reuse smem as h buffer
    u16* hb = (u16*)smem;          // [64 batch][16 hcol] u16 = 2KB

#pragma unroll
    for (int i = 0; i < 2; ++i)
#pragma unroll
    for (int jj = 0; jj < 2; ++jj) {
        // lane's 4 regs = gates i,f,g,o of ONE cell:
        const int hcl = ((wn + i * 16) >> 2) + q;   // hcol local 0..15
        const int bl  = wm + jj * 16 + fm;          // batch local 0..63
        const float4 b4 = *(const float4*)&bsumv[n0 + wn + i * 16 + q * 4];
        float gi = acc[i][jj][0] + b4.x;
        float gf = acc[i][jj][1] + b4.y;
        float gg = acc[i][jj][2] + b4.z;
        float go = acc[i][jj][3] + b4.w;
        // c layout [hcol_global][batch_global] -> 64B-coalesced per 16-lane group
        const int cidx = ((n0 >> 2) + hcl) * 512 + (row0 + bl);
        float c_old = cbuf[cidx];
        float is = sigmoid_fast(gi);
        float fs = sigmoid_fast(gf);
        float os = sigmoid_fast(go);
        float gt = tanh_fast(gg);
        float cn = fs * c_old + is * gt;
        float hn = os * tanh_fast(cn);
        cbuf[cidx] = cn;
        hb[bl * 16 + hcl] = f2h(hn);
    }
    __syncthreads();

    // coalesced output pass: thread t -> batch = t>>2, 4 hcols = (t&3)*4
    {
        const int bl = tid >> 2;
        const int hc4 = (tid & 3) * 4;
        const int grow = row0 + bl;
        const int gh = (n0 >> 2) + hc4;
        ushort4 h4 = *(const ushort4*)&hb[bl * 16 + hc4];
        const size_t ab = (size_t)grow * 1024;
        if (!IS_L1) {
            // h0(t) -> X-slot of A1[cur]
            *(ushort4*)&hdst[ab + gh] = h4;
        } else {
            // h1(t) -> h-slot of A1[nxt]
            *(ushort4*)&hdst[ab + 512 + gh] = h4;
            // hsum(t) = h0(t) + h1(t) -> X-slot of A0[nxt] + seq output
            ushort4 h0v = *(const ushort4*)&h0src[ab + gh];
            ushort4 s4;
            s4.x = f2h(h2f(h0v.x) + h2f(h4.x));
            s4.y = f2h(h2f(h0v.y) + h2f(h4.y));
            s4.z = f2h(h2f(h0v.z) + h2f(h4.z));
            s4.w = f2h(h2f(h0v.w) + h2f(h4.w));
            *(ushort4*)&hsumdst[ab + gh] = s4;
            *(ushort4*)&seqdst[(size_t)grow * 512 + gh] = s4;
        }
    }
}

// ------------------------------------------------------------------- MLP -----
// r14-exact: m97-structure 128x128 tile, 4 waves x 64x64 (4x4 16x16 frags),
// K=512 in 8 chunks of 64. gl_lds w16 staging with swizzle involution, 2 bufs
// x (A 16K | B 16K), full-drain __syncthreads loop. Named LDS pointers + swap.
template <int RELU, int FINAL>
__global__ __launch_bounds__(256) void mlp_gemm(
    const u16* __restrict__ A, const u16* __restrict__ Bw, const float* __restrict__ bias,
    u16* __restrict__ yh, float* __restrict__ yf32)
{
    __shared__ char smem[65536];   // 2 bufs x (A 16K | B 16K)

    const int tid = threadIdx.x;
    const int lane = tid & 63, wid = tid >> 6;
    const int row0 = blockIdx.y * 128;
    const int n0 = blockIdx.x * 128;
    const int wm = (wid >> 1) * 64, wn = (wid & 1) * 64;
    const int fm = lane & 15, q = lane >> 4;

    // staging: each tile = 1024 16B-units (128 rows x 8 units); wave w stages
    // units [w*256, w*256+256) via 4 instrs; global src pre-swizzled.
    int rS[4], cS[4];
#pragma unroll
    for (int i = 0; i < 4; ++i) {
        int s = wid * 256 + i * 64 + lane;
        rS[i] = s >> 3; cS[i] = ((s & 7) ^ (rS[i] & 7)) << 3;
    }
    size_t aO[4], bO[4];
#pragma unroll
    for (int i = 0; i < 4; ++i) {
        aO[i] = (size_t)(row0 + rS[i]) * 512 + cS[i];
        bO[i] = (size_t)(n0 + rS[i]) * 512 + cS[i];
    }
    const int dst0 = wid * 4096;

    f32x4 acc[4][4];
#pragma unroll
    for (int m = 0; m < 4; ++m)
#pragma unroll
        for (int n = 0; n < 4; ++n) acc[m][n] = (f32x4)0.f;

    auto stage = [&](char* buf, int k0) {
#pragma unroll
        for (int i = 0; i < 4; ++i) gl_lds16(A + aO[i] + k0, buf + dst0 + i * 1024);
#pragma unroll
        for (int i = 0; i < 4; ++i) gl_lds16(Bw + bO[i] + k0, buf + 16384 + dst0 + i * 1024);
    };

    char* pc = smem;            // current buffer
    char* pn = smem + 32768;    // next buffer

    stage(pc, 0);
    __syncthreads();

    for (int c = 0; c < 8; ++c) {
        if (c + 1 < 8) stage(pn, (c + 1) * 64);  // hides under compute

        const u16* sA = (const u16*)pc;
        const u16* sB = (const u16*)(pc + 16384);

#pragma unroll
        for (int kf = 0; kf < 2; ++kf) {
            const int cu = kf * 4 + q;
            f16x8 a[4], b[4];
#pragma unroll
            for (int m = 0; m < 4; ++m) a[m] = lds_read_sw(sA, wm + m * 16 + fm, cu);
#pragma unroll
            for (int n = 0; n < 4; ++n) b[n] = lds_read_sw(sB, wn + n * 16 + fm, cu);
#pragma unroll
            for (int m = 0; m < 4; ++m)
#pragma unroll
                for (int n = 0; n < 4; ++n)
                    acc[m][n] = __builtin_amdgcn_mfma_f32_16x16x32_f16(a[m], b[n], acc[m][n], 0, 0, 0);
        }

        __syncthreads();   // drains staging + LDS reads; next chunk resident
        char* t = pc; pc = pn; pn = t;
    }

    // Epilogue: two 64-row halves through sG [64][132] f32 (33.8KB, coalesced out)
    float* sG = (float*)smem;
#pragma unroll
    for (int h = 0; h < 2; ++h) {
        if ((wid >> 1) == h) {
#pragma unroll
            for (int m = 0; m < 4; ++m)
#pragma unroll
                for (int n = 0; n < 4; ++n)
#pragma unroll
                    for (int r = 0; r < 4; ++r) {
                        int row = m * 16 + q * 4 + r;   // local 0..63
                        int col = wn + n * 16 + fm;     // 0..127
                        sG[row * 132 + col] = acc[m][n][r];
                    }
        }
        __syncthreads();
        const int rloc = tid >> 2;
        const int cg = (tid & 3) * 32;
        const size_t r = (size_t)row0 + h * 64 + rloc;
#pragma unroll
        for (int cc = cg; cc < cg + 32; cc += 4) {
            float4 g = *(const float4*)&sG[rloc * 132 + cc];
            float4 b = *(const float4*)&bias[n0 + cc];
            float v0 = g.x + b.x, v1 = g.y + b.y, v2 = g.z + b.z, v3 = g.w + b.w;
            if (RELU) {
                v0 = fmaxf(v0, 0.f); v1 = fmaxf(v1, 0.f); v2 = fmaxf(v2, 0.f); v3 = fmaxf(v3, 0.f);
            }
            if (!FINAL) {
                ushort4 p;
                p.x = f2h(v0); p.y = f2h(v1); p.z = f2h(v2); p.w = f2h(v3);
                *(ushort4*)&yh[r * 512 + n0 + cc] = p;
            } else {
                int tt = (int)(r >> 9), bb = (int)(r & 511);  // seq row r = t*512 + b
                float4 o; o.x = v0; o.y = v1; o.z = v2; o.w = v3;
                *(float4*)&yf32[((size_t)bb * 128 + tt) * 512 + n0 + cc] = o;
            }
        }
        __syncthreads();   // protect sG before half-1 overwrite
    }
}

// ---------------------------------------------------------------- launch -----
extern "C" void kernel_launch(void* const* d_in, const int* in_sizes, int n_in,
                              void* d_out, int out_size, void* d_ws, size_t ws_size,
                              hipStream_t stream) {
    const float* x    = (const float*)d_in[0];
    const float* W_ih = (const float*)d_in[1];
    const float* W_hh = (const float*)d_in[2];
    const float* b_ih = (const float*)d_in[3];
    const float* b_hh = (const float*)d_in[4];
    const float* fc1w = (const float*)d_in[5];
    const float* fc1b = (const float*)d_in[6];
    const float* fc2w = (const float*)d_in[7];
    const float* fc2b = (const float*)d_in[8];
    const float* fc3w = (const float*)d_in[9];
    const float* fc3b = (const float*)d_in[10];

    char* ws = (char*)d_ws;
    u16* Bpack = (u16*)(ws);                          // 8,388,608 B
    u16* fcw   = (u16*)(ws + 8388608);                // 1,572,864 B
    float* bsum = (float*)(ws + 9961472);             // 16,384 B
    u16* A0[2] = { (u16*)(ws + 9977856),  (u16*)(ws + 11026432) };   // 1MB each
    u16* A1[2] = { (u16*)(ws + 12075008), (u16*)(ws + 13123584) };   // 1MB each
    float* c0 = (float*)(ws + 14172160);              // 1MB, layout [hcol][batch]
    float* c1 = (float*)(ws + 15220736);              // 1MB
    u16* seqb = (u16*)(ws + 20463616);                // 67,108,864 (reused as y2)
    // gb (LSTM-era) aliases the y1 (MLP-era) region — disjoint lifetimes.
    float* gb[2] = { (float*)(ws + 87572480), (float*)(ws + 87572480 + 4194304) };
    u16* y1   = (u16*)(ws + 87572480);                // 67,108,864
    float* out = (float*)d_out;

    prepack<<<dim3(512), dim3(256), 0, stream>>>(W_ih, W_hh, b_ih, b_hh, fc1w, fc2w, fc3w,
                                                 Bpack, bsum, fcw);
    initbufs<<<dim3(512), dim3(256), 0, stream>>>(x, A0[0], A1[0], c0, c1, gb[0]);

    const int LSTR = 2048 * 1024;
    for (int s = 0; s < 256; ++s) {
        int t = s >> 1, layer = s & 1, cur = t & 1, nxt = cur ^ 1;
        float* gR = gb[s & 1];
        float* gW = gb[(s + 1) & 1];
        if (!layer) {
            // completion: gates0(t) = gR + hsum(t-1)@Wih0 -> h0(t) into A1[cur] X-slot
            // partial:    gW = h1(t-1)@Whh1   (h1 from A1[cur] h-slot, W = layer1 k[512:1024))
            lstm_phase<0><<<dim3(512), dim3(256), 0, stream>>>(
                A0[cur], A1[cur], 512, Bpack, Bpack + LSTR + 512,
                gR, gW, bsum, c0,
                A1[cur], nullptr, nullptr, nullptr);
        } else {
            // completion: gates1(t) = gR + h0(t)@Wih1 -> h1(t) into A1[nxt] h-slot, hsum -> A0[nxt]
            // partial:    gW = h0(t)@Whh0     (h0 from A1[cur] X-slot, W = layer0 k[512:1024))
            lstm_phase<1><<<dim3(512), dim3(256), 0, stream>>>(
                A1[cur], A1[cur], 0, Bpack + LSTR, Bpack + 512,
                gR, gW, bsum + 2048, c1,
                A1[nxt], A1[cur], A0[nxt], seqb + (size_t)t * 262144);
        }
    }

    mlp_gemm<1, 0><<<dim3(4, 512), dim3(256), 0, stream>>>(seqb, fcw, fc1b, y1, nullptr);
    mlp_gemm<1, 0><<<dim3(4, 512), dim3(256), 0, stream>>>(y1, fcw + 512 * 512, fc2b, seqb, nullptr);
    mlp_gemm<0, 1><<<dim3(4, 512), dim3(256), 0, stream>>>(seqb, fcw + 2 * 512 * 512, fc3b, nullptr, out);
}

// Round 16
// 1925.219 us; speedup vs baseline: 1.0564x; 1.0564x over previous
//
#include <hip/hip_runtime.h>
#include <cstdint>
#include <cstddef>

// DecoderLSTM: 2-layer LSTM (B=512,H=512,T=128) + 3-layer MLP head.
// fp16 datapath, fp32 accum + fp32 cell state. K-split pipelining (round 5):
// gates_s = X_s@Wx + H_s@Wh; H-half computed one dispatch early by 256 partial
// blocks while 256 completion blocks finish the current step (512 blocks, 2/CU).
// Round 16: champion r12 structure (BK=64, depth-2 counted vmcnt — BK=128
// full-drain regressed in r15) with 4 LDS buffers so stage(c+2) is issued
// BEFORE the vmcnt wait (target = buffer consumed at c-2; its reads finished
// before the PREVIOUS barrier -> no WAR hazard). DMA gets 2 barrier-periods
// of slack; staging addr-VALU leaves the post-barrier critical path.
// Also: initbufs merged into prepack (one fewer serial dispatch).
// MLP = r14-exact (at its memory floor).

using u16 = unsigned short;
typedef __attribute__((ext_vector_type(8))) _Float16 f16x8;
typedef __attribute__((ext_vector_type(4))) float f32x4;

__device__ __forceinline__ u16 f2h(float f) {
    union { _Float16 h; u16 u; } v; v.h = (_Float16)f; return v.u;
}
__device__ __forceinline__ float h2f(u16 u) {
    union { u16 u; _Float16 h; } v; v.u = u; return (float)v.h;
}
__device__ __forceinline__ float tanh_fast(float v) {
    float a = fabsf(v);
    float t = __expf(-2.f * a);
    float r = (1.f - t) / (1.f + t);
    return copysignf(r, v);
}
__device__ __forceinline__ float sigmoid_fast(float v) {
    return 1.f / (1.f + __expf(-v));
}

__device__ __forceinline__ void gl_lds16(const u16* g, char* l) {
    __builtin_amdgcn_global_load_lds((const __attribute__((address_space(1))) char*)(const char*)g,
                                     (__attribute__((address_space(3))) char*)l, 16, 0, 0);
}

// Swizzled LDS read: tile [rows][64 f16] linear (128B rows = 8 x 16B units),
// unit u' holds global col-unit u'^(row&7). Involution applied to global src on
// stage and to the read index here (both sides, rule #21).
__device__ __forceinline__ f16x8 lds_read_sw(const u16* tile, int row, int cu) {
    int unit = (row << 3) | (cu ^ (row & 7));
    return *(const f16x8*)&tile[unit << 3];
}

// ---------------------------------------------------------------- prepack ----
// Bpack[l][np][k] (f16), np = hcol*4 + gate (i,f,g,o), k: 0..511 = W_ih, 512..1023 = W_hh.
// Also performs all buffer init (was initbufs): A0_0 X-slot = x, A1_0 h-slot = 0,
// c0/c1 = 0, gb0 = 0.
__global__ __launch_bounds__(256) void prepack(
    const float* __restrict__ W_ih, const float* __restrict__ W_hh,
    const float* __restrict__ b_ih, const float* __restrict__ b_hh,
    const float* __restrict__ fc1w, const float* __restrict__ fc2w, const float* __restrict__ fc3w,
    const float* __restrict__ x,
    u16* __restrict__ Bpack, float* __restrict__ bsumv, u16* __restrict__ fcw,
    u16* __restrict__ A0_0, u16* __restrict__ A1_0,
    float* __restrict__ c0, float* __restrict__ c1, float* __restrict__ gb0)
{
    int stride = gridDim.x * blockDim.x;
    int tid0 = blockIdx.x * blockDim.x + threadIdx.x;
    for (int idx = tid0; idx < 2 * 2048 * 1024; idx += stride) {
        int l = idx >> 21;
        int rem = idx & ((1 << 21) - 1);
        int np = rem >> 10;
        int k = rem & 1023;
        int n = (np & 3) * 512 + (np >> 2);
        float v = (k < 512) ? W_ih[((size_t)l * 2048 + n) * 512 + k]
                            : W_hh[((size_t)l * 2048 + n) * 512 + (k - 512)];
        Bpack[idx] = f2h(v);
    }
    for (int idx = tid0; idx < 2 * 2048; idx += stride) {
        int l = idx >> 11;
        int np = idx & 2047;
        int n = (np & 3) * 512 + (np >> 2);
        bsumv[idx] = b_ih[l * 2048 + n] + b_hh[l * 2048 + n];
    }
    for (int idx = tid0; idx < 3 * 512 * 512; idx += stride) {
        const float* w = idx < 262144 ? fc1w : (idx < 524288 ? fc2w : fc3w);
        fcw[idx] = f2h(w[idx & 262143]);
    }
    // --- buffer init (merged initbufs) ---
    for (int idx = tid0; idx < 512 * 512; idx += stride) {
        int row = idx >> 9, col = idx & 511;
        size_t b = (size_t)row * 1024;
        A0_0[b + col] = f2h(x[idx]);
        A1_0[b + 512 + col] = 0;     // h1(-1) = 0
        c0[idx] = 0.f;               // c layout [hcol][batch]
        c1[idx] = 0.f;
    }
    for (int idx = tid0; idx < 1048576; idx += stride) gb0[idx] = 0.f;  // H-half of step 0
}

// --------------------------------------------------------------- lstm phase --
// 512 blocks x 256 thr (2/CU). Blocks 0..255: completion (gates = gbufR + X@W_x,
// in-register epilogue). Blocks 256..511: partial (gbufW = H@W_h). 64 batch x
// 64 n'-cols, K=512 in 8 chunks of 64; depth-2 counted-vmcnt pipeline with
// FOUR 16KB buffers: stage(c+2) issued BEFORE the wait (its target buffer was
// consumed at c-2; those reads were complete before the previous barrier, and
// every wave has passed that barrier -> no WAR hazard). vmcnt ladder: at iter c
// outstanding = stages {c, c+1, c+2} = 12 loads -> vmcnt(8) waits exactly
// stage c; tail c=6 -> vmcnt(4), c=7 -> vmcnt(0). MFMA operands SWAPPED
// (gates^T = W.X^T): lane's 4 acc regs = gates i,f,g,o of ONE cell.
template <int IS_L1>
__global__ __launch_bounds__(256) void lstm_phase(
    const u16* __restrict__ Ax, const u16* __restrict__ Ah, int hoffH,
    const u16* __restrict__ Wc, const u16* __restrict__ Wp,
    const float* __restrict__ gbufR, float* __restrict__ gbufW,
    const float* __restrict__ bsumv, float* __restrict__ cbuf,
    u16* __restrict__ hdst, const u16* __restrict__ h0src,
    u16* __restrict__ hsumdst, u16* __restrict__ seqdst)
{
    __shared__ char smem[65536];   // 4 bufs x (A 8K | W 8K)

    const int id = blockIdx.x;
    const bool isPartial = id >= 256;
    const int rid = id & 255;
    const int xcd = rid & 7, slot = rid >> 3;
    const int nb = xcd * 4 + (slot & 3);   // 0..31
    const int rg = slot >> 2;              // 0..7
    const int n0 = nb * 64;
    const int row0 = rg * 64;
    const int tile = rg * 32 + nb;

    const u16* Abase = isPartial ? Ah : Ax;
    const int xoff = isPartial ? hoffH : 0;
    const u16* Wbase = isPartial ? Wp : Wc;

    const int tid = threadIdx.x;
    const int lane = tid & 63, wid = tid >> 6;
    const int wm = (wid >> 1) * 32, wn = (wid & 1) * 32;
    const int fm = lane & 15, q = lane >> 4;

    // staging: wave w stages 16B-units [w*128, w*128+128) of each 512-unit tile
    const int s0 = wid * 128 + lane, s1 = s0 + 64;
    const int r0s = s0 >> 3, c0s = ((s0 & 7) ^ (r0s & 7)) << 3;
    const int r1s = s1 >> 3, c1s = ((s1 & 7) ^ (r1s & 7)) << 3;
    const size_t aO0 = (size_t)(row0 + r0s) * 1024 + xoff + c0s;
    const size_t aO1 = (size_t)(row0 + r1s) * 1024 + xoff + c1s;
    const size_t bO0 = (size_t)(n0 + r0s) * 1024 + c0s;
    const size_t bO1 = (size_t)(n0 + r1s) * 1024 + c1s;
    const int d0 = wid * 2048, d1 = d0 + 1024;

    f32x4 acc[2][2];
    acc[0][0] = (f32x4)0.f; acc[0][1] = (f32x4)0.f;
    acc[1][0] = (f32x4)0.f; acc[1][1] = (f32x4)0.f;

    auto stage = [&](char* buf, int k0) {
        gl_lds16(Abase + aO0 + k0, buf + d0);
        gl_lds16(Abase + aO1 + k0, buf + d1);
        gl_lds16(Wbase + bO0 + k0, buf + 8192 + d0);
        gl_lds16(Wbase + bO1 + k0, buf + 8192 + d1);
    };

    char* p0 = smem;            // compute buffer (chunk c)
    char* p1 = smem + 16384;    // chunk c+1
    char* p2 = smem + 32768;    // stage target (chunk c+2)
    char* p3 = smem + 49152;    // oldest retired (chunk c-2's buffer)

    stage(p0, 0);
    stage(p1, 64);

    for (int c = 0; c < 8; ++c) {
        if (c < 6) stage(p2, (c + 2) * 64);   // early issue: WAR-safe (consumed at c-2)
        if (c < 6)      asm volatile("s_waitcnt vmcnt(8)" ::: "memory");
        else if (c == 6) asm volatile("s_waitcnt vmcnt(4)" ::: "memory");
        else             asm volatile("s_waitcnt vmcnt(0)" ::: "memory");
        __builtin_amdgcn_s_barrier();
        __builtin_amdgcn_sched_barrier(0);

        const u16* sA = (const u16*)p0;
        const u16* sB = (const u16*)(p0 + 8192);

#pragma unroll
        for (int kf = 0; kf < 2; ++kf) {
            const int cu = kf * 4 + q;
            f16x8 b0 = lds_read_sw(sB, wn + fm, cu);        // W rows wn..wn+15   (A-op)
            f16x8 b1 = lds_read_sw(sB, wn + 16 + fm, cu);   // W rows wn+16..+31
            f16x8 a0 = lds_read_sw(sA, wm + fm, cu);        // X rows wm..wm+15   (B-op)
            f16x8 a1 = lds_read_sw(sA, wm + 16 + fm, cu);   // X rows wm+16..+31
            // swapped: D = W · X^T ; acc[i][j] = n'-frag i, batch-frag j
            acc[0][0] = __builtin_amdgcn_mfma_f32_16x16x32_f16(b0, a0, acc[0][0], 0, 0, 0);
            acc[0][1] = __builtin_amdgcn_mfma_f32_16x16x32_f16(b0, a1, acc[0][1], 0, 0, 0);
            acc[1][0] = __builtin_amdgcn_mfma_f32_16x16x32_f16(b1, a0, acc[1][0], 0, 0, 0);
            acc[1][1] = __builtin_amdgcn_mfma_f32_16x16x32_f16(b1, a1, acc[1][1], 0, 0, 0);
        }

        char* t = p0; p0 = p1; p1 = p2; p2 = p3; p3 = t;
    }

    // ---------------- partial role: dump fragments to gbufW, done --------------
    if (isPartial) {
        float* dst = gbufW + (size_t)tile * 4096 + wid * 1024 + lane * 4;
        *(f32x4*)(dst +   0) = acc[0][0];
        *(f32x4*)(dst + 256) = acc[0][1];
        *(f32x4*)(dst + 512) = acc[1][0];
        *(f32x4*)(dst + 768) = acc[1][1];
        return;
    }

    // ---------------- completion role: add partial, in-register LSTM cell ------
    {
        const float* src = gbufR + (size_t)tile * 4096 + wid * 1024 + lane * 4;
        acc[0][0] += *(const f32x4*)(src +   0);
        acc[0][1] += *(const f32x4*)(src + 256);
        acc[1][0] += *(const f32x4*)(src + 512);
        acc[1][1] += *(const f32x4*)(src + 768);
    }

    __syncthreads();               // staging drained; reuse smem as h buffer
    u16* hb = (u16*)smem;          // [64 batch][16 hcol] u16 = 2KB

#pragma unroll
    for (int i = 0; i < 2; ++i)
#pragma unroll
    for (int jj = 0; jj < 2; ++jj) {
        // lane's 4 regs = gates i,f,g,o of ONE cell:
        const int hcl = ((wn + i * 16) >> 2) + q;   // hcol local 0..15
        const int bl  = wm + jj * 16 + fm;          // batch local 0..63
        const float4 b4 = *(const float4*)&bsumv[n0 + wn + i * 16 + q * 4];
        float gi = acc[i][jj][0] + b4.x;
        float gf = acc[i][jj][1] + b4.y;
        float gg = acc[i][jj][2] + b4.z;
        float go = acc[i][jj][3] + b4.w;
        // c layout [hcol_global][batch_global] -> 64B-coalesced per 16-lane group
        const int cidx = ((n0 >> 2) + hcl) * 512 + (row0 + bl);
        float c_old = cbuf[cidx];
        float is = sigmoid_fast(gi);
        float fs = sigmoid_fast(gf);
        float os = sigmoid_fast(go);
        float gt = tanh_fast(gg);
        float cn = fs * c_old + is * gt;
        float hn = os * tanh_fast(cn);
        cbuf[cidx] = cn;
        hb[bl * 16 + hcl] = f2h(hn);
    }
    __syncthreads();

    // coalesced output pass: thread t -> batch = t>>2, 4 hcols = (t&3)*4
    {
        const int bl = tid >> 2;
        const int hc4 = (tid & 3) * 4;
        const int grow = row0 + bl;
        const int gh = (n0 >> 2) + hc4;
        ushort4 h4 = *(const ushort4*)&hb[bl * 16 + hc4];
        const size_t ab = (size_t)grow * 1024;
        if (!IS_L1) {
            // h0(t) -> X-slot of A1[cur]
            *(ushort4*)&hdst[ab + gh] = h4;
        } else {
            // h1(t) -> h-slot of A1[nxt]
            *(ushort4*)&hdst[ab + 512 + gh] = h4;
            // hsum(t) = h0(t) + h1(t) -> X-slot of A0[nxt] + seq output
            ushort4 h0v = *(const ushort4*)&h0src[ab + gh];
            ushort4 s4;
            s4.x = f2h(h2f(h0v.x) + h2f(h4.x));
            s4.y = f2h(h2f(h0v.y) + h2f(h4.y));
            s4.z = f2h(h2f(h0v.z) + h2f(h4.z));
            s4.w = f2h(h2f(h0v.w) + h2f(h4.w));
            *(ushort4*)&hsumdst[ab + gh] = s4;
            *(ushort4*)&seqdst[(size_t)grow * 512 + gh] = s4;
        }
    }
}

// ------------------------------------------------------------------- MLP -----
// r14-exact: m97-structure 128x128 tile, 4 waves x 64x64 (4x4 16x16 frags),
// K=512 in 8 chunks of 64. gl_lds w16 staging with swizzle involution, 2 bufs
// x (A 16K | B 16K), full-drain __syncthreads loop. Named LDS pointers + swap.
template <int RELU, int FINAL>
__global__ __launch_bounds__(256) void mlp_gemm(
    const u16* __restrict__ A, const u16* __restrict__ Bw, const float* __restrict__ bias,
    u16* __restrict__ yh, float* __restrict__ yf32)
{
    __shared__ char smem[65536];   // 2 bufs x (A 16K | B 16K)

    const int tid = threadIdx.x;
    const int lane = tid & 63, wid = tid >> 6;
    const int row0 = blockIdx.y * 128;
    const int n0 = blockIdx.x * 128;
    const int wm = (wid >> 1) * 64, wn = (wid & 1) * 64;
    const int fm = lane & 15, q = lane >> 4;

    // staging: each tile = 1024 16B-units (128 rows x 8 units); wave w stages
    // units [w*256, w*256+256) via 4 instrs; global src pre-swizzled.
    int rS[4], cS[4];
#pragma unroll
    for (int i = 0; i < 4; ++i) {
        int s = wid * 256 + i * 64 + lane;
        rS[i] = s >> 3; cS[i] = ((s & 7) ^ (rS[i] & 7)) << 3;
    }
    size_t aO[4], bO[4];
#pragma unroll
    for (int i = 0; i < 4; ++i) {
        aO[i] = (size_t)(row0 + rS[i]) * 512 + cS[i];
        bO[i] = (size_t)(n0 + rS[i]) * 512 + cS[i];
    }
    const int dst0 = wid * 4096;

    f32x4 acc[4][4];
#pragma unroll
    for (int m = 0; m < 4; ++m)
#pragma unroll
        for (int n = 0; n < 4; ++n) acc[m][n] = (f32x4)0.f;

    auto stage = [&](char* buf, int k0) {
#pragma unroll
        for (int i = 0; i < 4; ++i) gl_lds16(A + aO[i] + k0, buf + dst0 + i * 1024);
#pragma unroll
        for (int i = 0; i < 4; ++i) gl_lds16(Bw + bO[i] + k0, buf + 16384 + dst0 + i * 1024);
    };

    char* pc = smem;            // current buffer
    char* pn = smem + 32768;    // next buffer

    stage(pc, 0);
    __syncthreads();

    for (int c = 0; c < 8; ++c) {
        if (c + 1 < 8) stage(pn, (c + 1) * 64);  // hides under compute

        const u16* sA = (const u16*)pc;
        const u16* sB = (const u16*)(pc + 16384);

#pragma unroll
        for (int kf = 0; kf < 2; ++kf) {
            const int cu = kf * 4 + q;
            f16x8 a[4], b[4];
#pragma unroll
            for (int m = 0; m < 4; ++m) a[m] = lds_read_sw(sA, wm + m * 16 + fm, cu);
#pragma unroll
            for (int n = 0; n < 4; ++n) b[n] = lds_read_sw(sB, wn + n * 16 + fm, cu);
#pragma unroll
            for (int m = 0; m < 4; ++m)
#pragma unroll
                for (int n = 0; n < 4; ++n)
                    acc[m][n] = __builtin_amdgcn_mfma_f32_16x16x32_f16(a[m], b[n], acc[m][n], 0, 0, 0);
        }

        __syncthreads();   // drains staging + LDS reads; next chunk resident
        char* t = pc; pc = pn; pn = t;
    }

    // Epilogue: two 64-row halves through sG [64][132] f32 (33.8KB, coalesced out)
    float* sG = (float*)smem;
#pragma unroll
    for (int h = 0; h < 2; ++h) {
        if ((wid >> 1) == h) {
#pragma unroll
            for (int m = 0; m < 4; ++m)
#pragma unroll
                for (int n = 0; n < 4; ++n)
#pragma unroll
                    for (int r = 0; r < 4; ++r) {
                        int row = m * 16 + q * 4 + r;   // local 0..63
                        int col = wn + n * 16 + fm;     // 0..127
                        sG[row * 132 + col] = acc[m][n][r];
                    }
        }
        __syncthreads();
        const int rloc = tid >> 2;
        const int cg = (tid & 3) * 32;
        const size_t r = (size_t)row0 + h * 64 + rloc;
#pragma unroll
        for (int cc = cg; cc < cg + 32; cc += 4) {
            float4 g = *(const float4*)&sG[rloc * 132 + cc];
            float4 b = *(const float4*)&bias[n0 + cc];
            float v0 = g.x + b.x, v1 = g.y + b.y, v2 = g.z + b.z, v3 = g.w + b.w;
            if (RELU) {
                v0 = fmaxf(v0, 0.f); v1 = fmaxf(v1, 0.f); v2 = fmaxf(v2, 0.f); v3 = fmaxf(v3, 0.f);
            }
            if (!FINAL) {
                ushort4 p;
                p.x = f2h(v0); p.y = f2h(v1); p.z = f2h(v2); p.w = f2h(v3);
                *(ushort4*)&yh[r * 512 + n0 + cc] = p;
            } else {
                int tt = (int)(r >> 9), bb = (int)(r & 511);  // seq row r = t*512 + b
                float4 o; o.x = v0; o.y = v1; o.z = v2; o.w = v3;
                *(float4*)&yf32[((size_t)bb * 128 + tt) * 512 + n0 + cc] = o;
            }
        }
        __syncthreads();   // protect sG before half-1 overwrite
    }
}

// ---------------------------------------------------------------- launch -----
extern "C" void kernel_launch(void* const* d_in, const int* in_sizes, int n_in,
                              void* d_out, int out_size, void* d_ws, size_t ws_size,
                              hipStream_t stream) {
    const float* x    = (const float*)d_in[0];
    const float* W_ih = (const float*)d_in[1];
    const float* W_hh = (const float*)d_in[2];
    const float* b_ih = (const float*)d_in[3];
    const float* b_hh = (const float*)d_in[4];
    const float* fc1w = (const float*)d_in[5];
    const float* fc1b = (const float*)d_in[6];
    const float* fc2w = (const float*)d_in[7];
    const float* fc2b = (const float*)d_in[8];
    const float* fc3w = (const float*)d_in[9];
    const float* fc3b = (const float*)d_in[10];

    char* ws = (char*)d_ws;
    u16* Bpack = (u16*)(ws);                          // 8,388,608 B
    u16* fcw   = (u16*)(ws + 8388608);                // 1,572,864 B
    float* bsum = (float*)(ws + 9961472);             // 16,384 B
    u16* A0[2] = { (u16*)(ws + 9977856),  (u16*)(ws + 11026432) };   // 1MB each
    u16* A1[2] = { (u16*)(ws + 12075008), (u16*)(ws + 13123584) };   // 1MB each
    float* c0 = (float*)(ws + 14172160);              // 1MB, layout [hcol][batch]
    float* c1 = (float*)(ws + 15220736);              // 1MB
    u16* seqb = (u16*)(ws + 20463616);                // 67,108,864 (reused as y2)
    // gb (LSTM-era) aliases the y1 (MLP-era) region — disjoint lifetimes.
    float* gb[2] = { (float*)(ws + 87572480), (float*)(ws + 87572480 + 4194304) };
    u16* y1   = (u16*)(ws + 87572480);                // 67,108,864
    float* out = (float*)d_out;

    prepack<<<dim3(512), dim3(256), 0, stream>>>(W_ih, W_hh, b_ih, b_hh, fc1w, fc2w, fc3w,
                                                 x, Bpack, bsum, fcw,
                                                 A0[0], A1[0], c0, c1, gb[0]);

    const int LSTR = 2048 * 1024;
    for (int s = 0; s < 256; ++s) {
        int t = s >> 1, layer = s & 1, cur = t & 1, nxt = cur ^ 1;
        float* gR = gb[s & 1];
        float* gW = gb[(s + 1) & 1];
        if (!layer) {
            // completion: gates0(t) = gR + hsum(t-1)@Wih0 -> h0(t) into A1[cur] X-slot
            // partial:    gW = h1(t-1)@Whh1   (h1 from A1[cur] h-slot, W = layer1 k[512:1024))
            lstm_phase<0><<<dim3(512), dim3(256), 0, stream>>>(
                A0[cur], A1[cur], 512, Bpack, Bpack + LSTR + 512,
                gR, gW, bsum, c0,
                A1[cur], nullptr, nullptr, nullptr);
        } else {
            // completion: gates1(t) = gR + h0(t)@Wih1 -> h1(t) into A1[nxt] h-slot, hsum -> A0[nxt]
            // partial:    gW = h0(t)@Whh0     (h0 from A1[cur] X-slot, W = layer0 k[512:1024))
            lstm_phase<1><<<dim3(512), dim3(256), 0, stream>>>(
                A1[cur], A1[cur], 0, Bpack + LSTR, Bpack + 512,
                gR, gW, bsum + 2048, c1,
                A1[nxt], A1[cur], A0[nxt], seqb + (size_t)t * 262144);
        }
    }

    mlp_gemm<1, 0><<<dim3(4, 512), dim3(256), 0, stream>>>(seqb, fcw, fc1b, y1, nullptr);
    mlp_gemm<1, 0><<<dim3(4, 512), dim3(256), 0, stream>>>(y1, fcw + 512 * 512, fc2b, seqb, nullptr);
    mlp_gemm<0, 1><<<dim3(4, 512), dim3(256), 0, stream>>>(seqb, fcw + 2 * 512 * 512, fc3b, nullptr, out);
}